// Round 1
// baseline (254.828 us; speedup 1.0000x reference)
//
#include <hip/hip_runtime.h>

// Strategy: the whole network is a pointwise function code = F(sigma),
// sigma in [0.5, 2.5).  Build a G_TAB-point lookup table of F (exact f32
// network eval) and linearly interpolate per pixel.  Lerp error
// ~h^2/8*|F''| + kink terms ~ <1e-5, threshold is ~1.3e-3.

#define G_TAB 2048
#define NK 441           // 21*21
#define UV 65536         // 256*256

// ws layout (floats)
#define OFF_TABLE 0
#define OFF_PET   (G_TAB*64)               // [441][64]
#define OFF_WVT   (OFF_PET + NK*64)        // [2][64][64]
#define OFF_OUTT  (OFF_WVT + 2*64*64)      // [2][64][64]
#define OFF_FF1T  (OFF_OUTT + 2*64*64)     // [2][64][256]
#define OFF_FF2T  (OFF_FF1T + 2*64*256)    // [2][256][64]
#define OFF_H1T   (OFF_FF2T + 2*256*64)    // [64][64]
#define OFF_H2T   (OFF_H1T + 64*64)        // [64][64]

// ---------------- prep: transpose weights to [k][out] for coalesced matvec ----
#define PREP_N (28224 + 8192 + 8192 + 32768 + 32768 + 4096 + 4096)  // 118336

__global__ __launch_bounds__(256) void prep_kernel(
    const float* __restrict__ pe_w, const float* __restrict__ in_w,
    const float* __restrict__ out_w, const float* __restrict__ ff1_w,
    const float* __restrict__ ff2_w, const float* __restrict__ h1_w,
    const float* __restrict__ h2_w, float* __restrict__ ws) {
  int t = blockIdx.x * 256 + threadIdx.x;
  if (t < 28224) {                       // peT[idx][e] = pe_w[e][idx]
    int e = t & 63, idx = t >> 6;
    ws[OFF_PET + t] = pe_w[e * 441 + idx];
    return;
  }
  t -= 28224;
  if (t < 8192) {                        // wvT[l][k][a] = in_w[l][128+a][k]
    int a = t & 63, k = (t >> 6) & 63, l = t >> 12;
    ws[OFF_WVT + t] = in_w[l * 12288 + (128 + a) * 64 + k];
    return;
  }
  t -= 8192;
  if (t < 8192) {                        // outT[l][a][e] = out_w[l][e][a]
    int e = t & 63, a = (t >> 6) & 63, l = t >> 12;
    ws[OFF_OUTT + t] = out_w[(l * 64 + e) * 64 + a];
    return;
  }
  t -= 8192;
  if (t < 32768) {                       // ff1T[l][k][a] = ff1_w[l][a][k]
    int a = t & 255, k = (t >> 8) & 63, l = t >> 14;
    ws[OFF_FF1T + t] = ff1_w[(l * 256 + a) * 64 + k];
    return;
  }
  t -= 32768;
  if (t < 32768) {                       // ff2T[l][k][e] = ff2_w[l][e][k]
    int e = t & 63, k = (t >> 6) & 255, l = t >> 14;
    ws[OFF_FF2T + t] = ff2_w[(l * 64 + e) * 256 + k];
    return;
  }
  t -= 32768;
  if (t < 4096) {                        // h1T[k][a] = h1_w[a][k]
    int a = t & 63, k = t >> 6;
    ws[OFF_H1T + t] = h1_w[a * 64 + k];
    return;
  }
  t -= 4096;
  if (t < 4096) {                        // h2T[a][c] = h2_w[c][a]
    int c = t & 63, a = t >> 6;
    ws[OFF_H2T + t] = h2_w[c * 64 + a];
    return;
  }
}

// ---------------- build: one wave per 4 sigma-grid rows, thread = channel -----

__device__ __forceinline__ void ln4(const float t[4], float g, float b, float out[4]) {
  float s1[4] = {t[0], t[1], t[2], t[3]};
#pragma unroll
  for (int o = 1; o < 64; o <<= 1) {
#pragma unroll
    for (int r = 0; r < 4; r++) s1[r] += __shfl_xor(s1[r], o, 64);
  }
  float d[4], s2[4];
#pragma unroll
  for (int r = 0; r < 4; r++) {
    d[r] = t[r] - s1[r] * (1.0f / 64.0f);
    s2[r] = d[r] * d[r];
  }
#pragma unroll
  for (int o = 1; o < 64; o <<= 1) {
#pragma unroll
    for (int r = 0; r < 4; r++) s2[r] += __shfl_xor(s2[r], o, 64);
  }
#pragma unroll
  for (int r = 0; r < 4; r++) {
    float inv = rsqrtf(s2[r] * (1.0f / 64.0f) + 1e-5f);
    out[r] = d[r] * inv * g + b;
  }
}

__global__ __launch_bounds__(64) void build_table_kernel(
    const float* __restrict__ pe_b, const float* __restrict__ in_b,
    const float* __restrict__ out_b, const float* __restrict__ ff1_b,
    const float* __restrict__ ff2_b, const float* __restrict__ ln1_g,
    const float* __restrict__ ln1_b, const float* __restrict__ ln2_g,
    const float* __restrict__ ln2_b, const float* __restrict__ h1_b,
    const float* __restrict__ h2_b, float* __restrict__ ws) {
  __shared__ float4 kern4[NK];   // gaussian kernel, 4 rows packed per idx
  __shared__ float4 xs4[64];
  __shared__ float4 vs4[64];
  __shared__ float4 ffs4[256];
  const int lane = threadIdx.x;
  const float* peT  = ws + OFF_PET;
  const float* wvT  = ws + OFF_WVT;
  const float* outT = ws + OFF_OUTT;
  const float* ff1T = ws + OFF_FF1T;
  const float* ff2T = ws + OFF_FF2T;
  const float* h1T  = ws + OFF_H1T;
  const float* h2T  = ws + OFF_H2T;

  const int g0 = blockIdx.x * 4;
  float inv2s2[4], sums[4] = {0.f, 0.f, 0.f, 0.f};
#pragma unroll
  for (int r = 0; r < 4; r++) {
    float sg = 0.5f + 2.0f * (float)(g0 + r) / (float)(G_TAB - 1);
    inv2s2[r] = 1.0f / (2.0f * sg * sg);
  }
  for (int idx = lane; idx < NK; idx += 64) {
    int di = idx / 21 - 10, dj = idx % 21 - 10;
    float nr2 = -(float)(di * di + dj * dj);
    float4 kv;
    kv.x = __expf(nr2 * inv2s2[0]);
    kv.y = __expf(nr2 * inv2s2[1]);
    kv.z = __expf(nr2 * inv2s2[2]);
    kv.w = __expf(nr2 * inv2s2[3]);
    kern4[idx] = kv;
    sums[0] += kv.x; sums[1] += kv.y; sums[2] += kv.z; sums[3] += kv.w;
  }
#pragma unroll
  for (int o = 1; o < 64; o <<= 1) {
#pragma unroll
    for (int r = 0; r < 4; r++) sums[r] += __shfl_xor(sums[r], o, 64);
  }
  float scale[4];
#pragma unroll
  for (int r = 0; r < 4; r++) scale[r] = 1.0f / sums[r];
  __syncthreads();

  // patch embed: x[e] = (sum_idx kern*peT)*scale + pe_b
  float acc[4] = {0.f, 0.f, 0.f, 0.f};
#pragma unroll 7
  for (int idx = 0; idx < NK; idx++) {
    float w = peT[idx * 64 + lane];
    float4 k4 = kern4[idx];
    acc[0] = fmaf(k4.x, w, acc[0]);
    acc[1] = fmaf(k4.y, w, acc[1]);
    acc[2] = fmaf(k4.z, w, acc[2]);
    acc[3] = fmaf(k4.w, w, acc[3]);
  }
  float x[4];
  {
    float pb = pe_b[lane];
#pragma unroll
    for (int r = 0; r < 4; r++) x[r] = fmaf(acc[r], scale[r], pb);
  }

  for (int l = 0; l < 2; l++) {
    __syncthreads();
    xs4[lane] = make_float4(x[0], x[1], x[2], x[3]);
    __syncthreads();
    // v = x @ wv^T + bv   (thread = a)
    float a4[4] = {0.f, 0.f, 0.f, 0.f};
    const float* W = wvT + l * 4096;
#pragma unroll 8
    for (int k = 0; k < 64; k++) {
      float w = W[k * 64 + lane];
      float4 xv = xs4[k];
      a4[0] = fmaf(xv.x, w, a4[0]);
      a4[1] = fmaf(xv.y, w, a4[1]);
      a4[2] = fmaf(xv.z, w, a4[2]);
      a4[3] = fmaf(xv.w, w, a4[3]);
    }
    float vb = in_b[l * 192 + 128 + lane];
    __syncthreads();
    vs4[lane] = make_float4(a4[0] + vb, a4[1] + vb, a4[2] + vb, a4[3] + vb);
    __syncthreads();
    // attn = v @ out_w^T + out_b   (thread = e)
    float b4[4] = {0.f, 0.f, 0.f, 0.f};
    const float* W2 = outT + l * 4096;
#pragma unroll 8
    for (int a = 0; a < 64; a++) {
      float w = W2[a * 64 + lane];
      float4 vv = vs4[a];
      b4[0] = fmaf(vv.x, w, b4[0]);
      b4[1] = fmaf(vv.y, w, b4[1]);
      b4[2] = fmaf(vv.z, w, b4[2]);
      b4[3] = fmaf(vv.w, w, b4[3]);
    }
    float ob = out_b[l * 64 + lane];
    float t[4];
#pragma unroll
    for (int r = 0; r < 4; r++) t[r] = x[r] + b4[r] + ob;
    ln4(t, ln1_g[l * 64 + lane], ln1_b[l * 64 + lane], x);

    __syncthreads();
    xs4[lane] = make_float4(x[0], x[1], x[2], x[3]);
    __syncthreads();
    // ffn1: pre[a] for a = lane + 64j
    float pre[4][4];
#pragma unroll
    for (int j = 0; j < 4; j++)
#pragma unroll
      for (int r = 0; r < 4; r++) pre[j][r] = 0.f;
    const float* F1 = ff1T + l * 16384;
#pragma unroll 4
    for (int k = 0; k < 64; k++) {
      float4 xv = xs4[k];
#pragma unroll
      for (int j = 0; j < 4; j++) {
        float w = F1[k * 256 + lane + 64 * j];
        pre[j][0] = fmaf(xv.x, w, pre[j][0]);
        pre[j][1] = fmaf(xv.y, w, pre[j][1]);
        pre[j][2] = fmaf(xv.z, w, pre[j][2]);
        pre[j][3] = fmaf(xv.w, w, pre[j][3]);
      }
    }
    __syncthreads();
#pragma unroll
    for (int j = 0; j < 4; j++) {
      float fb = ff1_b[l * 256 + lane + 64 * j];
      float p0 = fmaxf(pre[j][0] + fb, 0.f);
      float p1 = fmaxf(pre[j][1] + fb, 0.f);
      float p2 = fmaxf(pre[j][2] + fb, 0.f);
      float p3 = fmaxf(pre[j][3] + fb, 0.f);
      ffs4[lane + 64 * j] = make_float4(p0, p1, p2, p3);
    }
    __syncthreads();
    // ffn2
    float c4[4] = {0.f, 0.f, 0.f, 0.f};
    const float* F2 = ff2T + l * 16384;
#pragma unroll 8
    for (int k = 0; k < 256; k++) {
      float w = F2[k * 64 + lane];
      float4 fv = ffs4[k];
      c4[0] = fmaf(fv.x, w, c4[0]);
      c4[1] = fmaf(fv.y, w, c4[1]);
      c4[2] = fmaf(fv.z, w, c4[2]);
      c4[3] = fmaf(fv.w, w, c4[3]);
    }
    float fb2 = ff2_b[l * 64 + lane];
#pragma unroll
    for (int r = 0; r < 4; r++) t[r] = x[r] + c4[r] + fb2;
    ln4(t, ln2_g[l * 64 + lane], ln2_b[l * 64 + lane], x);
  }

  // head
  __syncthreads();
  xs4[lane] = make_float4(x[0], x[1], x[2], x[3]);
  __syncthreads();
  float a4[4] = {0.f, 0.f, 0.f, 0.f};
#pragma unroll 8
  for (int k = 0; k < 64; k++) {
    float w = h1T[k * 64 + lane];
    float4 xv = xs4[k];
    a4[0] = fmaf(xv.x, w, a4[0]);
    a4[1] = fmaf(xv.y, w, a4[1]);
    a4[2] = fmaf(xv.z, w, a4[2]);
    a4[3] = fmaf(xv.w, w, a4[3]);
  }
  {
    float hb = h1_b[lane];
#pragma unroll
    for (int r = 0; r < 4; r++) {
      float h = a4[r] + hb;
      a4[r] = h >= 0.f ? h : 0.1f * h;
    }
  }
  __syncthreads();
  vs4[lane] = make_float4(a4[0], a4[1], a4[2], a4[3]);
  __syncthreads();
  float c4[4] = {0.f, 0.f, 0.f, 0.f};
#pragma unroll 8
  for (int a = 0; a < 64; a++) {
    float w = h2T[a * 64 + lane];
    float4 hv = vs4[a];
    c4[0] = fmaf(hv.x, w, c4[0]);
    c4[1] = fmaf(hv.y, w, c4[1]);
    c4[2] = fmaf(hv.z, w, c4[2]);
    c4[3] = fmaf(hv.w, w, c4[3]);
  }
  float hb2 = h2_b[lane];
#pragma unroll
  for (int r = 0; r < 4; r++)
    ws[OFF_TABLE + (g0 + r) * 64 + lane] = c4[r] + hb2;
}

// ---------------- interp: gather rows (lane=channel, coalesced), lerp,
// ---------------- transpose via padded LDS, write out (lane=v, coalesced) ----

__global__ __launch_bounds__(128) void interp_kernel(
    const float* __restrict__ sigma, const float* __restrict__ ws,
    float* __restrict__ out, int npix) {
  __shared__ float buf[2][64 * 65];   // pad 65: (lane+c)%32 -> 2-way, free
  __shared__ int   ridx[2][64];
  __shared__ float rfrac[2][64];
  const int wave = threadIdx.x >> 6;
  const int lane = threadIdx.x & 63;
  const float* table = ws + OFF_TABLE;
  const int pix0 = blockIdx.x * 128 + wave * 64;

  int p = pix0 + lane;
  float sg = (p < npix) ? sigma[p] : 1.0f;
  float t = (sg - 0.5f) * ((float)(G_TAB - 1) * 0.5f);  // /h, h=2/(G-1)
  t = fmaxf(t, 0.0f);
  int i0 = (int)t;
  if (i0 > G_TAB - 2) i0 = G_TAB - 2;
  float f = t - (float)i0;
  ridx[wave][lane] = i0 * 64;
  rfrac[wave][lane] = f;
  __syncthreads();

#pragma unroll 8
  for (int k = 0; k < 64; k++) {
    int rb = ridx[wave][k];
    float fr = rfrac[wave][k];
    float a = table[rb + lane];         // coalesced 256B row read (L2)
    float b = table[rb + 64 + lane];
    buf[wave][k * 65 + lane] = fmaf(fr, b - a, a);
  }
  __syncthreads();

  int pp = pix0 + lane;
  if (pp < npix) {
    int bimg = pp >> 16;
    int rr = pp & (UV - 1);
    float* obase = out + (size_t)bimg * 64 * UV + rr;
#pragma unroll
    for (int c = 0; c < 64; c++) {
      obase[(size_t)c * UV] = buf[wave][lane * 65 + c];  // coalesced over lanes
    }
  }
}

extern "C" void kernel_launch(void* const* d_in, const int* in_sizes, int n_in,
                              void* d_out, int out_size, void* d_ws, size_t ws_size,
                              hipStream_t stream) {
  const float* sigma = (const float*)d_in[0];
  const float* pe_w  = (const float*)d_in[1];
  const float* pe_b  = (const float*)d_in[2];
  const float* in_w  = (const float*)d_in[3];
  const float* in_b  = (const float*)d_in[4];
  const float* out_w = (const float*)d_in[5];
  const float* out_b = (const float*)d_in[6];
  const float* ff1_w = (const float*)d_in[7];
  const float* ff1_b = (const float*)d_in[8];
  const float* ff2_w = (const float*)d_in[9];
  const float* ff2_b = (const float*)d_in[10];
  const float* ln1_g = (const float*)d_in[11];
  const float* ln1_b = (const float*)d_in[12];
  const float* ln2_g = (const float*)d_in[13];
  const float* ln2_b = (const float*)d_in[14];
  const float* h1_w  = (const float*)d_in[15];
  const float* h1_b  = (const float*)d_in[16];
  const float* h2_w  = (const float*)d_in[17];
  const float* h2_b  = (const float*)d_in[18];
  float* ws  = (float*)d_ws;
  float* out = (float*)d_out;
  int npix = in_sizes[0];

  prep_kernel<<<(PREP_N + 255) / 256, 256, 0, stream>>>(
      pe_w, in_w, out_w, ff1_w, ff2_w, h1_w, h2_w, ws);
  build_table_kernel<<<G_TAB / 4, 64, 0, stream>>>(
      pe_b, in_b, out_b, ff1_b, ff2_b, ln1_g, ln1_b, ln2_g, ln2_b,
      h1_b, h2_b, ws);
  interp_kernel<<<(npix + 127) / 128, 128, 0, stream>>>(sigma, ws, out, npix);
}

// Round 2
// 245.188 us; speedup vs baseline: 1.0393x; 1.0393x over previous
//
#include <hip/hip_runtime.h>

// Strategy: the whole network is a pointwise function code = F(sigma),
// sigma in [0.5, 2.5).  Build a G_TAB-point lookup table of F (exact f32
// network eval) and linearly interpolate per pixel.  Lerp error
// ~h^2/8*|F''| + kink terms; measured absmax 4.9e-4 vs threshold 1.3e-3.
//
// R2: table stored as interleaved float2 {F[i],F[i+1]} so the per-pixel
// gather is one dwordx2 instead of two dwords; nontemporal output stores;
// deeper unrolls in build to hide L2 latency at low occupancy.

#define G_TAB 2048
#define NK 441           // 21*21
#define UV 65536         // 256*256

// ws layout (floats)
#define OFF_TABLE 0                        // [2048][64][2] interleaved pairs
#define OFF_PET   (G_TAB*128)              // [441][64]
#define OFF_WVT   (OFF_PET + NK*64)        // [2][64][64]
#define OFF_OUTT  (OFF_WVT + 2*64*64)      // [2][64][64]
#define OFF_FF1T  (OFF_OUTT + 2*64*64)     // [2][64][256]
#define OFF_FF2T  (OFF_FF1T + 2*64*256)    // [2][256][64]
#define OFF_H1T   (OFF_FF2T + 2*256*64)    // [64][64]
#define OFF_H2T   (OFF_H1T + 64*64)        // [64][64]

// ---------------- prep: transpose weights to [k][out] for coalesced matvec ----
#define PREP_N (28224 + 8192 + 8192 + 32768 + 32768 + 4096 + 4096)  // 118336

__global__ __launch_bounds__(256) void prep_kernel(
    const float* __restrict__ pe_w, const float* __restrict__ in_w,
    const float* __restrict__ out_w, const float* __restrict__ ff1_w,
    const float* __restrict__ ff2_w, const float* __restrict__ h1_w,
    const float* __restrict__ h2_w, float* __restrict__ ws) {
  int t = blockIdx.x * 256 + threadIdx.x;
  if (t < 28224) {                       // peT[idx][e] = pe_w[e][idx]
    int e = t & 63, idx = t >> 6;
    ws[OFF_PET + t] = pe_w[e * 441 + idx];
    return;
  }
  t -= 28224;
  if (t < 8192) {                        // wvT[l][k][a] = in_w[l][128+a][k]
    int a = t & 63, k = (t >> 6) & 63, l = t >> 12;
    ws[OFF_WVT + t] = in_w[l * 12288 + (128 + a) * 64 + k];
    return;
  }
  t -= 8192;
  if (t < 8192) {                        // outT[l][a][e] = out_w[l][e][a]
    int e = t & 63, a = (t >> 6) & 63, l = t >> 12;
    ws[OFF_OUTT + t] = out_w[(l * 64 + e) * 64 + a];
    return;
  }
  t -= 8192;
  if (t < 32768) {                       // ff1T[l][k][a] = ff1_w[l][a][k]
    int a = t & 255, k = (t >> 8) & 63, l = t >> 14;
    ws[OFF_FF1T + t] = ff1_w[(l * 256 + a) * 64 + k];
    return;
  }
  t -= 32768;
  if (t < 32768) {                       // ff2T[l][k][e] = ff2_w[l][e][k]
    int e = t & 63, k = (t >> 6) & 255, l = t >> 14;
    ws[OFF_FF2T + t] = ff2_w[(l * 64 + e) * 256 + k];
    return;
  }
  t -= 32768;
  if (t < 4096) {                        // h1T[k][a] = h1_w[a][k]
    int a = t & 63, k = t >> 6;
    ws[OFF_H1T + t] = h1_w[a * 64 + k];
    return;
  }
  t -= 4096;
  if (t < 4096) {                        // h2T[a][c] = h2_w[c][a]
    int c = t & 63, a = t >> 6;
    ws[OFF_H2T + t] = h2_w[c * 64 + a];
    return;
  }
}

// ---------------- build: one wave per 4 sigma-grid rows, thread = channel -----

__device__ __forceinline__ void ln4(const float t[4], float g, float b, float out[4]) {
  float s1[4] = {t[0], t[1], t[2], t[3]};
#pragma unroll
  for (int o = 1; o < 64; o <<= 1) {
#pragma unroll
    for (int r = 0; r < 4; r++) s1[r] += __shfl_xor(s1[r], o, 64);
  }
  float d[4], s2[4];
#pragma unroll
  for (int r = 0; r < 4; r++) {
    d[r] = t[r] - s1[r] * (1.0f / 64.0f);
    s2[r] = d[r] * d[r];
  }
#pragma unroll
  for (int o = 1; o < 64; o <<= 1) {
#pragma unroll
    for (int r = 0; r < 4; r++) s2[r] += __shfl_xor(s2[r], o, 64);
  }
#pragma unroll
  for (int r = 0; r < 4; r++) {
    float inv = rsqrtf(s2[r] * (1.0f / 64.0f) + 1e-5f);
    out[r] = d[r] * inv * g + b;
  }
}

__global__ __launch_bounds__(64) void build_table_kernel(
    const float* __restrict__ pe_b, const float* __restrict__ in_b,
    const float* __restrict__ out_b, const float* __restrict__ ff1_b,
    const float* __restrict__ ff2_b, const float* __restrict__ ln1_g,
    const float* __restrict__ ln1_b, const float* __restrict__ ln2_g,
    const float* __restrict__ ln2_b, const float* __restrict__ h1_b,
    const float* __restrict__ h2_b, float* __restrict__ ws) {
  __shared__ float4 kern4[NK];   // gaussian kernel, 4 rows packed per idx
  __shared__ float4 xs4[64];
  __shared__ float4 vs4[64];
  __shared__ float4 ffs4[256];
  const int lane = threadIdx.x;
  const float* peT  = ws + OFF_PET;
  const float* wvT  = ws + OFF_WVT;
  const float* outT = ws + OFF_OUTT;
  const float* ff1T = ws + OFF_FF1T;
  const float* ff2T = ws + OFF_FF2T;
  const float* h1T  = ws + OFF_H1T;
  const float* h2T  = ws + OFF_H2T;

  const int g0 = blockIdx.x * 4;
  float inv2s2[4], sums[4] = {0.f, 0.f, 0.f, 0.f};
#pragma unroll
  for (int r = 0; r < 4; r++) {
    float sg = 0.5f + 2.0f * (float)(g0 + r) / (float)(G_TAB - 1);
    inv2s2[r] = 1.0f / (2.0f * sg * sg);
  }
  for (int idx = lane; idx < NK; idx += 64) {
    int di = idx / 21 - 10, dj = idx % 21 - 10;
    float nr2 = -(float)(di * di + dj * dj);
    float4 kv;
    kv.x = __expf(nr2 * inv2s2[0]);
    kv.y = __expf(nr2 * inv2s2[1]);
    kv.z = __expf(nr2 * inv2s2[2]);
    kv.w = __expf(nr2 * inv2s2[3]);
    kern4[idx] = kv;
    sums[0] += kv.x; sums[1] += kv.y; sums[2] += kv.z; sums[3] += kv.w;
  }
#pragma unroll
  for (int o = 1; o < 64; o <<= 1) {
#pragma unroll
    for (int r = 0; r < 4; r++) sums[r] += __shfl_xor(sums[r], o, 64);
  }
  float scale[4];
#pragma unroll
  for (int r = 0; r < 4; r++) scale[r] = 1.0f / sums[r];
  __syncthreads();

  // patch embed: x[e] = (sum_idx kern*peT)*scale + pe_b
  float acc[4] = {0.f, 0.f, 0.f, 0.f};
#pragma unroll 9
  for (int idx = 0; idx < NK; idx++) {
    float w = peT[idx * 64 + lane];
    float4 k4 = kern4[idx];
    acc[0] = fmaf(k4.x, w, acc[0]);
    acc[1] = fmaf(k4.y, w, acc[1]);
    acc[2] = fmaf(k4.z, w, acc[2]);
    acc[3] = fmaf(k4.w, w, acc[3]);
  }
  float x[4];
  {
    float pb = pe_b[lane];
#pragma unroll
    for (int r = 0; r < 4; r++) x[r] = fmaf(acc[r], scale[r], pb);
  }

  for (int l = 0; l < 2; l++) {
    __syncthreads();
    xs4[lane] = make_float4(x[0], x[1], x[2], x[3]);
    __syncthreads();
    // v = x @ wv^T + bv   (thread = a)
    float a4[4] = {0.f, 0.f, 0.f, 0.f};
    const float* W = wvT + l * 4096;
#pragma unroll 16
    for (int k = 0; k < 64; k++) {
      float w = W[k * 64 + lane];
      float4 xv = xs4[k];
      a4[0] = fmaf(xv.x, w, a4[0]);
      a4[1] = fmaf(xv.y, w, a4[1]);
      a4[2] = fmaf(xv.z, w, a4[2]);
      a4[3] = fmaf(xv.w, w, a4[3]);
    }
    float vb = in_b[l * 192 + 128 + lane];
    __syncthreads();
    vs4[lane] = make_float4(a4[0] + vb, a4[1] + vb, a4[2] + vb, a4[3] + vb);
    __syncthreads();
    // attn = v @ out_w^T + out_b   (thread = e)
    float b4[4] = {0.f, 0.f, 0.f, 0.f};
    const float* W2 = outT + l * 4096;
#pragma unroll 16
    for (int a = 0; a < 64; a++) {
      float w = W2[a * 64 + lane];
      float4 vv = vs4[a];
      b4[0] = fmaf(vv.x, w, b4[0]);
      b4[1] = fmaf(vv.y, w, b4[1]);
      b4[2] = fmaf(vv.z, w, b4[2]);
      b4[3] = fmaf(vv.w, w, b4[3]);
    }
    float ob = out_b[l * 64 + lane];
    float t[4];
#pragma unroll
    for (int r = 0; r < 4; r++) t[r] = x[r] + b4[r] + ob;
    ln4(t, ln1_g[l * 64 + lane], ln1_b[l * 64 + lane], x);

    __syncthreads();
    xs4[lane] = make_float4(x[0], x[1], x[2], x[3]);
    __syncthreads();
    // ffn1: pre[a] for a = lane + 64j
    float pre[4][4];
#pragma unroll
    for (int j = 0; j < 4; j++)
#pragma unroll
      for (int r = 0; r < 4; r++) pre[j][r] = 0.f;
    const float* F1 = ff1T + l * 16384;
#pragma unroll 8
    for (int k = 0; k < 64; k++) {
      float4 xv = xs4[k];
#pragma unroll
      for (int j = 0; j < 4; j++) {
        float w = F1[k * 256 + lane + 64 * j];
        pre[j][0] = fmaf(xv.x, w, pre[j][0]);
        pre[j][1] = fmaf(xv.y, w, pre[j][1]);
        pre[j][2] = fmaf(xv.z, w, pre[j][2]);
        pre[j][3] = fmaf(xv.w, w, pre[j][3]);
      }
    }
    __syncthreads();
#pragma unroll
    for (int j = 0; j < 4; j++) {
      float fb = ff1_b[l * 256 + lane + 64 * j];
      float p0 = fmaxf(pre[j][0] + fb, 0.f);
      float p1 = fmaxf(pre[j][1] + fb, 0.f);
      float p2 = fmaxf(pre[j][2] + fb, 0.f);
      float p3 = fmaxf(pre[j][3] + fb, 0.f);
      ffs4[lane + 64 * j] = make_float4(p0, p1, p2, p3);
    }
    __syncthreads();
    // ffn2
    float c4[4] = {0.f, 0.f, 0.f, 0.f};
    const float* F2 = ff2T + l * 16384;
#pragma unroll 16
    for (int k = 0; k < 256; k++) {
      float w = F2[k * 64 + lane];
      float4 fv = ffs4[k];
      c4[0] = fmaf(fv.x, w, c4[0]);
      c4[1] = fmaf(fv.y, w, c4[1]);
      c4[2] = fmaf(fv.z, w, c4[2]);
      c4[3] = fmaf(fv.w, w, c4[3]);
    }
    float fb2 = ff2_b[l * 64 + lane];
#pragma unroll
    for (int r = 0; r < 4; r++) t[r] = x[r] + c4[r] + fb2;
    ln4(t, ln2_g[l * 64 + lane], ln2_b[l * 64 + lane], x);
  }

  // head
  __syncthreads();
  xs4[lane] = make_float4(x[0], x[1], x[2], x[3]);
  __syncthreads();
  float a4[4] = {0.f, 0.f, 0.f, 0.f};
#pragma unroll 16
  for (int k = 0; k < 64; k++) {
    float w = h1T[k * 64 + lane];
    float4 xv = xs4[k];
    a4[0] = fmaf(xv.x, w, a4[0]);
    a4[1] = fmaf(xv.y, w, a4[1]);
    a4[2] = fmaf(xv.z, w, a4[2]);
    a4[3] = fmaf(xv.w, w, a4[3]);
  }
  {
    float hb = h1_b[lane];
#pragma unroll
    for (int r = 0; r < 4; r++) {
      float h = a4[r] + hb;
      a4[r] = h >= 0.f ? h : 0.1f * h;
    }
  }
  __syncthreads();
  vs4[lane] = make_float4(a4[0], a4[1], a4[2], a4[3]);
  __syncthreads();
  float c4[4] = {0.f, 0.f, 0.f, 0.f};
#pragma unroll 16
  for (int a = 0; a < 64; a++) {
    float w = h2T[a * 64 + lane];
    float4 hv = vs4[a];
    c4[0] = fmaf(hv.x, w, c4[0]);
    c4[1] = fmaf(hv.y, w, c4[1]);
    c4[2] = fmaf(hv.z, w, c4[2]);
    c4[3] = fmaf(hv.w, w, c4[3]);
  }
  float hb2 = h2_b[lane];
  // table2 interleaved write: entry i = {F[i], F[i+1]}
  // row g writes slot0 of entry g and slot1 of entry g-1 (all-distinct, no race).
  // entry 2047 slot1 never written, never read (i0 <= 2046).
#pragma unroll
  for (int r = 0; r < 4; r++) {
    float val = c4[r] + hb2;
    int g = g0 + r;
    ws[OFF_TABLE + g * 128 + 2 * lane] = val;
    if (g > 0) ws[OFF_TABLE + (g - 1) * 128 + 2 * lane + 1] = val;
  }
}

// ---------------- interp: gather float2 pairs (lane=channel, coalesced), lerp,
// ---------------- transpose via padded LDS, write out (lane=v, coalesced, nt) -

__global__ __launch_bounds__(128) void interp_kernel(
    const float* __restrict__ sigma, const float* __restrict__ ws,
    float* __restrict__ out, int npix) {
  __shared__ float buf[2][64 * 65];   // pad 65: 2-way bank alias only (free)
  __shared__ int   ridx[2][64];
  __shared__ float rfrac[2][64];
  const int wave = threadIdx.x >> 6;
  const int lane = threadIdx.x & 63;
  const float2* __restrict__ table2 = (const float2*)(ws + OFF_TABLE);
  const int pix0 = blockIdx.x * 128 + wave * 64;

  int p = pix0 + lane;
  float sg = (p < npix) ? sigma[p] : 1.0f;
  float t = (sg - 0.5f) * ((float)(G_TAB - 1) * 0.5f);  // /h, h=2/(G-1)
  t = fmaxf(t, 0.0f);
  int i0 = (int)t;
  if (i0 > G_TAB - 2) i0 = G_TAB - 2;
  float f = t - (float)i0;
  ridx[wave][lane] = i0 * 64;          // float2-index base of entry i0
  rfrac[wave][lane] = f;
  __syncthreads();

#pragma unroll 16
  for (int k = 0; k < 64; k++) {
    int rb = ridx[wave][k];
    float fr = rfrac[wave][k];
    float2 tv = table2[rb + lane];      // one coalesced dwordx2 (512B/wave)
    buf[wave][k * 65 + lane] = fmaf(fr, tv.y - tv.x, tv.x);
  }
  __syncthreads();

  int pp = pix0 + lane;
  if (pp < npix) {
    int bimg = pp >> 16;
    int rr = pp & (UV - 1);
    float* obase = out + (size_t)bimg * 64 * UV + rr;
#pragma unroll
    for (int c = 0; c < 64; c++) {
      // coalesced over lanes (256B/instr), nontemporal: streaming write-once
      __builtin_nontemporal_store(buf[wave][lane * 65 + c],
                                  obase + (size_t)c * UV);
    }
  }
}

extern "C" void kernel_launch(void* const* d_in, const int* in_sizes, int n_in,
                              void* d_out, int out_size, void* d_ws, size_t ws_size,
                              hipStream_t stream) {
  const float* sigma = (const float*)d_in[0];
  const float* pe_w  = (const float*)d_in[1];
  const float* pe_b  = (const float*)d_in[2];
  const float* in_w  = (const float*)d_in[3];
  const float* in_b  = (const float*)d_in[4];
  const float* out_w = (const float*)d_in[5];
  const float* out_b = (const float*)d_in[6];
  const float* ff1_w = (const float*)d_in[7];
  const float* ff1_b = (const float*)d_in[8];
  const float* ff2_w = (const float*)d_in[9];
  const float* ff2_b = (const float*)d_in[10];
  const float* ln1_g = (const float*)d_in[11];
  const float* ln1_b = (const float*)d_in[12];
  const float* ln2_g = (const float*)d_in[13];
  const float* ln2_b = (const float*)d_in[14];
  const float* h1_w  = (const float*)d_in[15];
  const float* h1_b  = (const float*)d_in[16];
  const float* h2_w  = (const float*)d_in[17];
  const float* h2_b  = (const float*)d_in[18];
  float* ws  = (float*)d_ws;
  float* out = (float*)d_out;
  int npix = in_sizes[0];

  prep_kernel<<<(PREP_N + 255) / 256, 256, 0, stream>>>(
      pe_w, in_w, out_w, ff1_w, ff2_w, h1_w, h2_w, ws);
  build_table_kernel<<<G_TAB / 4, 64, 0, stream>>>(
      pe_b, in_b, out_b, ff1_b, ff2_b, ln1_g, ln1_b, ln2_g, ln2_b,
      h1_b, h2_b, ws);
  interp_kernel<<<(npix + 127) / 128, 128, 0, stream>>>(sigma, ws, out, npix);
}

// Round 3
// 235.896 us; speedup vs baseline: 1.0803x; 1.0394x over previous
//
#include <hip/hip_runtime.h>
#include <hip/hip_fp16.h>

// Strategy: the whole network is a pointwise function code = F(sigma),
// sigma in [0.5, 2.5).  Build a G_TAB-point lookup table of F (exact f32
// network eval) and linearly interpolate per pixel.  Measured lerp absmax
// 4.9e-4 vs threshold 1.3e-3.
//
// R3: (a) build restructured: block=4 waves per 4-row group, weights k-split
// 4-ways across waves (disjoint -> same L2 traffic, 4x latency parallelism,
// 8 waves/CU instead of 2); (b) table stored as half2 {F[i],F[i+1]} -- one
// dword gather per (pixel,channel), half the L2 gather traffic; fp16 quant
// error <= 0.066*2^-11 ~ 3e-5, negligible.

#define G_TAB 2048
#define NK 441           // 21*21
#define UV 65536         // 256*256

// ws layout (float units)
#define OFF_TABLE 0                        // half2[2048][64] = 131072 floats
#define OFF_PET   131072                   // [441][64]
#define OFF_WVT   (OFF_PET + NK*64)        // [2][64][64]
#define OFF_OUTT  (OFF_WVT + 2*64*64)      // [2][64][64]
#define OFF_FF1T  (OFF_OUTT + 2*64*64)     // [2][64][256]
#define OFF_FF2T  (OFF_FF1T + 2*64*256)    // [2][256][64]
#define OFF_H1T   (OFF_FF2T + 2*256*64)    // [64][64]
#define OFF_H2T   (OFF_H1T + 64*64)        // [64][64]

// ---------------- prep: transpose weights to [k][out] for coalesced matvec ----
#define PREP_N (28224 + 8192 + 8192 + 32768 + 32768 + 4096 + 4096)  // 118336

__global__ __launch_bounds__(256) void prep_kernel(
    const float* __restrict__ pe_w, const float* __restrict__ in_w,
    const float* __restrict__ out_w, const float* __restrict__ ff1_w,
    const float* __restrict__ ff2_w, const float* __restrict__ h1_w,
    const float* __restrict__ h2_w, float* __restrict__ ws) {
  int t = blockIdx.x * 256 + threadIdx.x;
  if (t < 28224) {                       // peT[idx][e] = pe_w[e][idx]
    int e = t & 63, idx = t >> 6;
    ws[OFF_PET + t] = pe_w[e * 441 + idx];
    return;
  }
  t -= 28224;
  if (t < 8192) {                        // wvT[l][k][a] = in_w[l][128+a][k]
    int a = t & 63, k = (t >> 6) & 63, l = t >> 12;
    ws[OFF_WVT + t] = in_w[l * 12288 + (128 + a) * 64 + k];
    return;
  }
  t -= 8192;
  if (t < 8192) {                        // outT[l][a][e] = out_w[l][e][a]
    int e = t & 63, a = (t >> 6) & 63, l = t >> 12;
    ws[OFF_OUTT + t] = out_w[(l * 64 + e) * 64 + a];
    return;
  }
  t -= 8192;
  if (t < 32768) {                       // ff1T[l][k][a] = ff1_w[l][a][k]
    int a = t & 255, k = (t >> 8) & 63, l = t >> 14;
    ws[OFF_FF1T + t] = ff1_w[(l * 256 + a) * 64 + k];
    return;
  }
  t -= 32768;
  if (t < 32768) {                       // ff2T[l][k][e] = ff2_w[l][e][k]
    int e = t & 63, k = (t >> 6) & 255, l = t >> 14;
    ws[OFF_FF2T + t] = ff2_w[(l * 64 + e) * 256 + k];
    return;
  }
  t -= 32768;
  if (t < 4096) {                        // h1T[k][a] = h1_w[a][k]
    int a = t & 63, k = t >> 6;
    ws[OFF_H1T + t] = h1_w[a * 64 + k];
    return;
  }
  t -= 4096;
  if (t < 4096) {                        // h2T[a][c] = h2_w[c][a]
    int c = t & 63, a = t >> 6;
    ws[OFF_H2T + t] = h2_w[c * 64 + a];
    return;
  }
}

// ---------------- build: block = 4 waves, 4 table rows, k-split across waves -

__device__ __forceinline__ void ln4(const float t[4], float g, float b, float out[4]) {
  float s1[4] = {t[0], t[1], t[2], t[3]};
#pragma unroll
  for (int o = 1; o < 64; o <<= 1) {
#pragma unroll
    for (int r = 0; r < 4; r++) s1[r] += __shfl_xor(s1[r], o, 64);
  }
  float d[4], s2[4];
#pragma unroll
  for (int r = 0; r < 4; r++) {
    d[r] = t[r] - s1[r] * (1.0f / 64.0f);
    s2[r] = d[r] * d[r];
  }
#pragma unroll
  for (int o = 1; o < 64; o <<= 1) {
#pragma unroll
    for (int r = 0; r < 4; r++) s2[r] += __shfl_xor(s2[r], o, 64);
  }
#pragma unroll
  for (int r = 0; r < 4; r++) {
    float inv = rsqrtf(s2[r] * (1.0f / 64.0f) + 1e-5f);
    out[r] = d[r] * inv * g + b;
  }
}

__global__ __launch_bounds__(256) void build_table_kernel(
    const float* __restrict__ pe_b, const float* __restrict__ in_b,
    const float* __restrict__ out_b, const float* __restrict__ ff1_b,
    const float* __restrict__ ff2_b, const float* __restrict__ ln1_g,
    const float* __restrict__ ln1_b, const float* __restrict__ ln2_g,
    const float* __restrict__ ln2_b, const float* __restrict__ h1_b,
    const float* __restrict__ h2_b, float* __restrict__ ws) {
  __shared__ float4 kern4[NK];     // gaussian kernel, 4 rows packed
  __shared__ float4 xs4[64];       // broadcast vector for current matvec
  __shared__ float4 ffs4[256];     // ffn hidden
  __shared__ float4 part[4][256];  // per-wave partial sums
  const int tid = threadIdx.x;
  const int wave = tid >> 6, lane = tid & 63;
  const float* peT  = ws + OFF_PET;
  const float* wvT  = ws + OFF_WVT;
  const float* outT = ws + OFF_OUTT;
  const float* ff1T = ws + OFF_FF1T;
  const float* ff2T = ws + OFF_FF2T;
  const float* h1T  = ws + OFF_H1T;
  const float* h2T  = ws + OFF_H2T;

  const int g0 = blockIdx.x * 4;
  float inv2s2[4];
#pragma unroll
  for (int r = 0; r < 4; r++) {
    float sg = 0.5f + 2.0f * (float)(g0 + r) / (float)(G_TAB - 1);
    inv2s2[r] = 1.0f / (2.0f * sg * sg);
  }
  // gaussian kernel + normalization (whole block cooperates)
  float4 ps = make_float4(0.f, 0.f, 0.f, 0.f);
  for (int idx = tid; idx < NK; idx += 256) {
    int di = idx / 21 - 10, dj = idx % 21 - 10;
    float nr2 = -(float)(di * di + dj * dj);
    float4 kv;
    kv.x = __expf(nr2 * inv2s2[0]);
    kv.y = __expf(nr2 * inv2s2[1]);
    kv.z = __expf(nr2 * inv2s2[2]);
    kv.w = __expf(nr2 * inv2s2[3]);
    kern4[idx] = kv;
    ps.x += kv.x; ps.y += kv.y; ps.z += kv.z; ps.w += kv.w;
  }
#pragma unroll
  for (int o = 1; o < 64; o <<= 1) {
    ps.x += __shfl_xor(ps.x, o, 64);
    ps.y += __shfl_xor(ps.y, o, 64);
    ps.z += __shfl_xor(ps.z, o, 64);
    ps.w += __shfl_xor(ps.w, o, 64);
  }
  if (lane == 0) part[wave][0] = ps;
  __syncthreads();
  float scale4[4];
  {
    float4 a = part[0][0], b = part[1][0], c = part[2][0], d = part[3][0];
    scale4[0] = 1.0f / (a.x + b.x + c.x + d.x);
    scale4[1] = 1.0f / (a.y + b.y + c.y + d.y);
    scale4[2] = 1.0f / (a.z + b.z + c.z + d.z);
    scale4[3] = 1.0f / (a.w + b.w + c.w + d.w);
  }
  __syncthreads();   // part reuse below

  // patch embed: idx range split across waves
  {
    int ib = wave * 111;
    int ie = ib + 111; if (ie > NK) ie = NK;
    float4 acc = make_float4(0.f, 0.f, 0.f, 0.f);
    for (int idx = ib; idx < ie; idx++) {
      float w = peT[idx * 64 + lane];
      float4 kv = kern4[idx];
      acc.x = fmaf(kv.x, w, acc.x);
      acc.y = fmaf(kv.y, w, acc.y);
      acc.z = fmaf(kv.z, w, acc.z);
      acc.w = fmaf(kv.w, w, acc.w);
    }
    part[wave][lane] = acc;
  }
  __syncthreads();
  float x4[4];
  {
    float4 a = part[0][lane], b = part[1][lane], c = part[2][lane], d = part[3][lane];
    float pb = pe_b[lane];
    x4[0] = fmaf(a.x + b.x + c.x + d.x, scale4[0], pb);
    x4[1] = fmaf(a.y + b.y + c.y + d.y, scale4[1], pb);
    x4[2] = fmaf(a.z + b.z + c.z + d.z, scale4[2], pb);
    x4[3] = fmaf(a.w + b.w + c.w + d.w, scale4[3], pb);
  }
  __syncthreads();
  if (wave == 0) xs4[lane] = make_float4(x4[0], x4[1], x4[2], x4[3]);
  __syncthreads();

  for (int l = 0; l < 2; l++) {
    // v-proj: k split 4x16
    {
      const float* W = wvT + l * 4096 + wave * 16 * 64;
      float4 acc = make_float4(0.f, 0.f, 0.f, 0.f);
#pragma unroll
      for (int k = 0; k < 16; k++) {
        float w = W[k * 64 + lane];
        float4 xv = xs4[wave * 16 + k];
        acc.x = fmaf(xv.x, w, acc.x);
        acc.y = fmaf(xv.y, w, acc.y);
        acc.z = fmaf(xv.z, w, acc.z);
        acc.w = fmaf(xv.w, w, acc.w);
      }
      part[wave][lane] = acc;
    }
    __syncthreads();
    {
      float4 a = part[0][lane], b = part[1][lane], c = part[2][lane], d = part[3][lane];
      float vb = in_b[l * 192 + 128 + lane];
      __syncthreads();
      if (wave == 0)
        xs4[lane] = make_float4(a.x + b.x + c.x + d.x + vb,
                                a.y + b.y + c.y + d.y + vb,
                                a.z + b.z + c.z + d.z + vb,
                                a.w + b.w + c.w + d.w + vb);
    }
    __syncthreads();
    // out-proj: a split 4x16
    {
      const float* W = outT + l * 4096 + wave * 16 * 64;
      float4 acc = make_float4(0.f, 0.f, 0.f, 0.f);
#pragma unroll
      for (int a = 0; a < 16; a++) {
        float w = W[a * 64 + lane];
        float4 vv = xs4[wave * 16 + a];
        acc.x = fmaf(vv.x, w, acc.x);
        acc.y = fmaf(vv.y, w, acc.y);
        acc.z = fmaf(vv.z, w, acc.z);
        acc.w = fmaf(vv.w, w, acc.w);
      }
      part[wave][lane] = acc;
    }
    __syncthreads();
    {
      float4 a = part[0][lane], b = part[1][lane], c = part[2][lane], d = part[3][lane];
      float ob = out_b[l * 64 + lane];
      float t[4];
      t[0] = x4[0] + a.x + b.x + c.x + d.x + ob;
      t[1] = x4[1] + a.y + b.y + c.y + d.y + ob;
      t[2] = x4[2] + a.z + b.z + c.z + d.z + ob;
      t[3] = x4[3] + a.w + b.w + c.w + d.w + ob;
      ln4(t, ln1_g[l * 64 + lane], ln1_b[l * 64 + lane], x4);
    }
    __syncthreads();
    if (wave == 0) xs4[lane] = make_float4(x4[0], x4[1], x4[2], x4[3]);
    __syncthreads();
    // ffn1: k split 4x16, 256 outputs
    {
      const float* F1 = ff1T + l * 16384 + wave * 16 * 256;
      float4 acc[4];
#pragma unroll
      for (int j = 0; j < 4; j++) acc[j] = make_float4(0.f, 0.f, 0.f, 0.f);
#pragma unroll
      for (int k = 0; k < 16; k++) {
        float4 xv = xs4[wave * 16 + k];
#pragma unroll
        for (int j = 0; j < 4; j++) {
          float w = F1[k * 256 + lane + 64 * j];
          acc[j].x = fmaf(xv.x, w, acc[j].x);
          acc[j].y = fmaf(xv.y, w, acc[j].y);
          acc[j].z = fmaf(xv.z, w, acc[j].z);
          acc[j].w = fmaf(xv.w, w, acc[j].w);
        }
      }
#pragma unroll
      for (int j = 0; j < 4; j++) part[wave][lane + 64 * j] = acc[j];
    }
    __syncthreads();
    {
      float4 a = part[0][tid], b = part[1][tid], c = part[2][tid], d = part[3][tid];
      float fb = ff1_b[l * 256 + tid];
      float4 s;
      s.x = fmaxf(a.x + b.x + c.x + d.x + fb, 0.f);
      s.y = fmaxf(a.y + b.y + c.y + d.y + fb, 0.f);
      s.z = fmaxf(a.z + b.z + c.z + d.z + fb, 0.f);
      s.w = fmaxf(a.w + b.w + c.w + d.w + fb, 0.f);
      __syncthreads();
      ffs4[tid] = s;
    }
    __syncthreads();
    // ffn2: k split 4x64
    {
      const float* F2 = ff2T + l * 16384 + wave * 64 * 64;
      float4 acc = make_float4(0.f, 0.f, 0.f, 0.f);
#pragma unroll 16
      for (int k = 0; k < 64; k++) {
        float w = F2[k * 64 + lane];
        float4 fv = ffs4[wave * 64 + k];
        acc.x = fmaf(fv.x, w, acc.x);
        acc.y = fmaf(fv.y, w, acc.y);
        acc.z = fmaf(fv.z, w, acc.z);
        acc.w = fmaf(fv.w, w, acc.w);
      }
      part[wave][lane] = acc;
    }
    __syncthreads();
    {
      float4 a = part[0][lane], b = part[1][lane], c = part[2][lane], d = part[3][lane];
      float fb2 = ff2_b[l * 64 + lane];
      float t[4];
      t[0] = x4[0] + a.x + b.x + c.x + d.x + fb2;
      t[1] = x4[1] + a.y + b.y + c.y + d.y + fb2;
      t[2] = x4[2] + a.z + b.z + c.z + d.z + fb2;
      t[3] = x4[3] + a.w + b.w + c.w + d.w + fb2;
      ln4(t, ln2_g[l * 64 + lane], ln2_b[l * 64 + lane], x4);
    }
    __syncthreads();
    if (wave == 0) xs4[lane] = make_float4(x4[0], x4[1], x4[2], x4[3]);
    __syncthreads();
  }

  // head layer 1 (leaky relu)
  {
    const float* W = h1T + wave * 16 * 64;
    float4 acc = make_float4(0.f, 0.f, 0.f, 0.f);
#pragma unroll
    for (int k = 0; k < 16; k++) {
      float w = W[k * 64 + lane];
      float4 xv = xs4[wave * 16 + k];
      acc.x = fmaf(xv.x, w, acc.x);
      acc.y = fmaf(xv.y, w, acc.y);
      acc.z = fmaf(xv.z, w, acc.z);
      acc.w = fmaf(xv.w, w, acc.w);
    }
    part[wave][lane] = acc;
  }
  __syncthreads();
  {
    float4 a = part[0][lane], b = part[1][lane], c = part[2][lane], d = part[3][lane];
    float hb = h1_b[lane];
    float h0 = a.x + b.x + c.x + d.x + hb;
    float h1 = a.y + b.y + c.y + d.y + hb;
    float h2 = a.z + b.z + c.z + d.z + hb;
    float h3 = a.w + b.w + c.w + d.w + hb;
    h0 = h0 >= 0.f ? h0 : 0.1f * h0;
    h1 = h1 >= 0.f ? h1 : 0.1f * h1;
    h2 = h2 >= 0.f ? h2 : 0.1f * h2;
    h3 = h3 >= 0.f ? h3 : 0.1f * h3;
    __syncthreads();
    if (wave == 0) xs4[lane] = make_float4(h0, h1, h2, h3);
  }
  __syncthreads();
  // head layer 2 + table write (half, interleaved {F[i],F[i+1]})
  {
    const float* W = h2T + wave * 16 * 64;
    float4 acc = make_float4(0.f, 0.f, 0.f, 0.f);
#pragma unroll
    for (int a = 0; a < 16; a++) {
      float w = W[a * 64 + lane];
      float4 hv = xs4[wave * 16 + a];
      acc.x = fmaf(hv.x, w, acc.x);
      acc.y = fmaf(hv.y, w, acc.y);
      acc.z = fmaf(hv.z, w, acc.z);
      acc.w = fmaf(hv.w, w, acc.w);
    }
    part[wave][lane] = acc;
  }
  __syncthreads();
  {
    float4 a = part[0][lane], b = part[1][lane], c = part[2][lane], d = part[3][lane];
    float hb2 = h2_b[lane];
    float c0 = a.x + b.x + c.x + d.x + hb2;
    float c1 = a.y + b.y + c.y + d.y + hb2;
    float c2 = a.z + b.z + c.z + d.z + hb2;
    float c3 = a.w + b.w + c.w + d.w + hb2;
    // wave w owns table row g0+w
    float val = (wave == 0) ? c0 : (wave == 1) ? c1 : (wave == 2) ? c2 : c3;
    int g = g0 + wave;
    __half hv = __float2half(val);
    __half* tabh = (__half*)ws;
    tabh[(g * 64 + lane) * 2] = hv;                       // slot0 of entry g
    if (g > 0) tabh[((g - 1) * 64 + lane) * 2 + 1] = hv;  // slot1 of entry g-1
    // entry G_TAB-1 slot1 never written, never read (i0 clamped to G_TAB-2)
  }
}

// ---------------- interp: gather half2 pairs (lane=channel, coalesced), lerp,
// ---------------- transpose via padded LDS, write out (lane=v, coalesced, nt) -

__global__ __launch_bounds__(128) void interp_kernel(
    const float* __restrict__ sigma, const float* __restrict__ ws,
    float* __restrict__ out, int npix) {
  __shared__ float buf[2][64 * 65];   // pad 65: 2-way bank alias only (free)
  __shared__ float2 rif[2][64];       // x = (i0*64) as int bits, y = frac
  const int wave = threadIdx.x >> 6;
  const int lane = threadIdx.x & 63;
  const __half2* __restrict__ tab2 = (const __half2*)ws;
  const int pix0 = blockIdx.x * 128 + wave * 64;

  int p = pix0 + lane;
  float sg = (p < npix) ? sigma[p] : 1.0f;
  float t = (sg - 0.5f) * ((float)(G_TAB - 1) * 0.5f);  // /h, h=2/(G-1)
  t = fmaxf(t, 0.0f);
  int i0 = (int)t;
  if (i0 > G_TAB - 2) i0 = G_TAB - 2;
  float f = t - (float)i0;
  rif[wave][lane] = make_float2(__int_as_float(i0 * 64), f);
  __syncthreads();

#pragma unroll 16
  for (int k = 0; k < 64; k++) {
    float2 rf = rif[wave][k];
    int rb = __float_as_int(rf.x);
    float2 ab = __half22float2(tab2[rb + lane]);  // one coalesced dword/lane
    buf[wave][k * 65 + lane] = fmaf(rf.y, ab.y - ab.x, ab.x);
  }
  __syncthreads();

  int pp = pix0 + lane;
  if (pp < npix) {
    int bimg = pp >> 16;
    int rr = pp & (UV - 1);
    float* obase = out + (size_t)bimg * 64 * UV + rr;
#pragma unroll
    for (int c = 0; c < 64; c++) {
      // coalesced over lanes (256B/instr), nontemporal: streaming write-once
      __builtin_nontemporal_store(buf[wave][lane * 65 + c],
                                  obase + (size_t)c * UV);
    }
  }
}

extern "C" void kernel_launch(void* const* d_in, const int* in_sizes, int n_in,
                              void* d_out, int out_size, void* d_ws, size_t ws_size,
                              hipStream_t stream) {
  const float* sigma = (const float*)d_in[0];
  const float* pe_w  = (const float*)d_in[1];
  const float* pe_b  = (const float*)d_in[2];
  const float* in_w  = (const float*)d_in[3];
  const float* in_b  = (const float*)d_in[4];
  const float* out_w = (const float*)d_in[5];
  const float* out_b = (const float*)d_in[6];
  const float* ff1_w = (const float*)d_in[7];
  const float* ff1_b = (const float*)d_in[8];
  const float* ff2_w = (const float*)d_in[9];
  const float* ff2_b = (const float*)d_in[10];
  const float* ln1_g = (const float*)d_in[11];
  const float* ln1_b = (const float*)d_in[12];
  const float* ln2_g = (const float*)d_in[13];
  const float* ln2_b = (const float*)d_in[14];
  const float* h1_w  = (const float*)d_in[15];
  const float* h1_b  = (const float*)d_in[16];
  const float* h2_w  = (const float*)d_in[17];
  const float* h2_b  = (const float*)d_in[18];
  float* ws  = (float*)d_ws;
  float* out = (float*)d_out;
  int npix = in_sizes[0];

  prep_kernel<<<(PREP_N + 255) / 256, 256, 0, stream>>>(
      pe_w, in_w, out_w, ff1_w, ff2_w, h1_w, h2_w, ws);
  build_table_kernel<<<G_TAB / 4, 256, 0, stream>>>(
      pe_b, in_b, out_b, ff1_b, ff2_b, ln1_g, ln1_b, ln2_g, ln2_b,
      h1_b, h2_b, ws);
  interp_kernel<<<(npix + 127) / 128, 128, 0, stream>>>(sigma, ws, out, npix);
}